// Round 7
// baseline (560.959 us; speedup 1.0000x reference)
//
#include <hip/hip_runtime.h>
#include <math.h>

#define HDIM 128

#define BSHIFT 9
#define BW 512                  // nodes per bucket (dst >> 9)
#define BCAP 16384              // slots per bucket in tmp
#define NBKMAX 256
#define CHUNK 8192              // edges per bucket_bin block

typedef __attribute__((ext_vector_type(8))) __bf16 bf16x8;
typedef __attribute__((ext_vector_type(16))) float f32x16;
typedef unsigned int uint32;
typedef unsigned short u16;

__device__ __forceinline__ float bflo(uint32 v) { return __uint_as_float(v << 16); }
__device__ __forceinline__ float bfhi(uint32 v) { return __uint_as_float(v & 0xffff0000u); }

// ---------------- CSR build: bucketed two-pass (write-amp ~1) ----------------

__global__ __launch_bounds__(256) void bucket_bin(
    const int* __restrict__ ei, int E_, int nbk,
    int* __restrict__ bucketCnt, uint32* __restrict__ tmp)
{
    __shared__ int cnt[NBKMAX];
    __shared__ int gbase[NBKMAX];
    const int t = threadIdx.x;
    const int start = blockIdx.x * CHUNK;
    const int end = min(start + CHUNK, E_);

    for (int i = t; i < nbk; i += 256) cnt[i] = 0;
    __syncthreads();
    for (int e = start + t; e < end; e += 256)
        atomicAdd(&cnt[ei[E_ + e] >> BSHIFT], 1);
    __syncthreads();
    for (int i = t; i < nbk; i += 256) {
        int c = cnt[i];
        gbase[i] = c ? atomicAdd(&bucketCnt[i], c) : 0;
    }
    __syncthreads();
    for (int i = t; i < nbk; i += 256) cnt[i] = 0;
    __syncthreads();
    for (int e = start + t; e < end; e += 256) {
        int d = ei[E_ + e];
        int s = ei[e];
        int b = d >> BSHIFT;
        int r = atomicAdd(&cnt[b], 1);
        tmp[(size_t)b * BCAP + gbase[b] + r] =
            ((uint32)(d & (BW - 1)) << 17) | (uint32)s;
    }
}

__global__ void bucket_scan(const int* __restrict__ bucketCnt, int* __restrict__ bucketBase,
                            int nbk, int* __restrict__ off, int N_, int E_) {
    __shared__ int sd[256];
    int t = threadIdx.x;
    int v = (t < nbk) ? bucketCnt[t] : 0;
    sd[t] = v;
    __syncthreads();
    for (int ofs = 1; ofs < 256; ofs <<= 1) {
        int add = (t >= ofs) ? sd[t - ofs] : 0;
        __syncthreads();
        sd[t] += add;
        __syncthreads();
    }
    if (t < nbk) bucketBase[t] = sd[t] - v;
    if (t == 0) off[N_] = E_;
}

__global__ __launch_bounds__(256) void bucket_csr(
    const uint32* __restrict__ tmp, const int* __restrict__ bucketCnt,
    const int* __restrict__ bucketBase,
    int* __restrict__ off, int* __restrict__ srcs, int N_)
{
    __shared__ int lc[BW];
    __shared__ int lo[BW];
    __shared__ int sp[256];
    const int b = blockIdx.x, t = threadIdx.x;
    const int cnt = bucketCnt[b], base = bucketBase[b];
    const uint32* tp = tmp + (size_t)b * BCAP;

    lc[2 * t] = 0; lc[2 * t + 1] = 0;
    __syncthreads();
    for (int i = t; i < cnt; i += 256) atomicAdd(&lc[tp[i] >> 17], 1);
    __syncthreads();

    int a0 = lc[2 * t], a1 = lc[2 * t + 1];
    int ps = a0 + a1;
    sp[t] = ps;
    __syncthreads();
    for (int ofs = 1; ofs < 256; ofs <<= 1) {
        int add = (t >= ofs) ? sp[t - ofs] : 0;
        __syncthreads();
        sp[t] += add;
        __syncthreads();
    }
    int pexc = sp[t] - ps;
    lo[2 * t] = pexc; lo[2 * t + 1] = pexc + a0;
    __syncthreads();

    for (int i = t; i < BW; i += 256) {
        int node = b * BW + i;
        if (node < N_) off[node] = base + lo[i];
    }
    lc[2 * t] = lo[2 * t]; lc[2 * t + 1] = lo[2 * t + 1];
    __syncthreads();
    for (int i = t; i < cnt; i += 256) {
        uint32 p = tp[i];
        int dl = p >> 17, s = p & 0x1FFFF;
        int pos = base + atomicAdd(&lc[dl], 1);
        srcs[pos] = s;
    }
}

// ---------------- casts ----------------

__global__ void cast_x(const float* __restrict__ x, uint32* __restrict__ xb, int n2) {
    int i = blockIdx.x * 256 + threadIdx.x;
    if (i >= n2) return;
    float2 v = ((const float2*)x)[i];
    __bf16 a = (__bf16)v.x, b = (__bf16)v.y;
    xb[i] = (uint32)__builtin_bit_cast(u16, a) | ((uint32)__builtin_bit_cast(u16, b) << 16);
}

__global__ void cast_weights(const float* __restrict__ a, const float* __restrict__ b,
                             const float* __restrict__ c, const float* __restrict__ d,
                             const float* __restrict__ e, const float* __restrict__ f,
                             __bf16* __restrict__ out) {
    int i = blockIdx.x * 256 + threadIdx.x;  // 6*16384
    int which = i >> 14, j = i & 16383;
    float v;
    switch (which) {
        case 0: v = a[j]; break;
        case 1: v = b[j]; break;
        case 2: v = c[j]; break;
        case 3: v = d[j]; break;
        case 4: v = e[j]; break;
        default: v = f[j]; break;
    }
    out[i] = (__bf16)v;
}

// ---------------- gather-max: 1 wave/node, 16 lanes x 16B per row ----------------

__global__ __launch_bounds__(256) void gather_max(
    const uint32* __restrict__ hb, uint32* __restrict__ mb,
    const int* __restrict__ off, const int* __restrict__ srcs, int n_nodes)
{
    const int w = threadIdx.x >> 6, lane = threadIdx.x & 63;
    const int node = blockIdx.x * 4 + w;
    if (node >= n_nodes) return;
    const int es = lane >> 4, ch = lane & 15;
    const int e0 = off[node], e1 = off[node + 1];
    const uint4* hp = (const uint4*)hb;

    float m0 = -INFINITY, m1 = -INFINITY, m2 = -INFINITY, m3 = -INFINITY;
    float m4 = -INFINITY, m5 = -INFINITY, m6 = -INFINITY, m7 = -INFINITY;

    int e = e0 + es;
    for (; e + 4 < e1; e += 8) {
        int s0 = srcs[e], s1 = srcs[e + 4];
        uint4 v0 = hp[(size_t)s0 * 16 + ch];
        uint4 v1 = hp[(size_t)s1 * 16 + ch];
        m0 = fmaxf(m0, bflo(v0.x)); m1 = fmaxf(m1, bfhi(v0.x));
        m2 = fmaxf(m2, bflo(v0.y)); m3 = fmaxf(m3, bfhi(v0.y));
        m4 = fmaxf(m4, bflo(v0.z)); m5 = fmaxf(m5, bfhi(v0.z));
        m6 = fmaxf(m6, bflo(v0.w)); m7 = fmaxf(m7, bfhi(v0.w));
        m0 = fmaxf(m0, bflo(v1.x)); m1 = fmaxf(m1, bfhi(v1.x));
        m2 = fmaxf(m2, bflo(v1.y)); m3 = fmaxf(m3, bfhi(v1.y));
        m4 = fmaxf(m4, bflo(v1.z)); m5 = fmaxf(m5, bfhi(v1.z));
        m6 = fmaxf(m6, bflo(v1.w)); m7 = fmaxf(m7, bfhi(v1.w));
    }
    if (e < e1) {
        uint4 v0 = hp[(size_t)srcs[e] * 16 + ch];
        m0 = fmaxf(m0, bflo(v0.x)); m1 = fmaxf(m1, bfhi(v0.x));
        m2 = fmaxf(m2, bflo(v0.y)); m3 = fmaxf(m3, bfhi(v0.y));
        m4 = fmaxf(m4, bflo(v0.z)); m5 = fmaxf(m5, bfhi(v0.z));
        m6 = fmaxf(m6, bflo(v0.w)); m7 = fmaxf(m7, bfhi(v0.w));
    }

#define RED(m) m = fmaxf(m, __shfl_xor(m, 16)); m = fmaxf(m, __shfl_xor(m, 32));
    RED(m0) RED(m1) RED(m2) RED(m3) RED(m4) RED(m5) RED(m6) RED(m7)
#undef RED

    if (es == 0) {
        uint4 r = make_uint4(0u, 0u, 0u, 0u);
        if (e1 > e0) {
            r.x = (__float_as_uint(m0) >> 16) | (__float_as_uint(m1) & 0xffff0000u);
            r.y = (__float_as_uint(m2) >> 16) | (__float_as_uint(m3) & 0xffff0000u);
            r.z = (__float_as_uint(m4) >> 16) | (__float_as_uint(m5) & 0xffff0000u);
            r.w = (__float_as_uint(m6) >> 16) | (__float_as_uint(m7) & 0xffff0000u);
        }
        ((uint4*)mb)[(size_t)node * 16 + ch] = r;
    }
}

// ---------------- dense GEMM, LDS-free: A-frags straight from global ----------------
// A-frag for mfma_32x32x16_bf16 = 16 contiguous bytes of one row -> dwordx4 loads.
// Each row consumed by exactly one wave; weights L1-resident. No LDS, no barrier.

__global__ __launch_bounds__(256) void gemm_layer(
    const u16* __restrict__ mb, const u16* __restrict__ hb,
    const u16* __restrict__ res, u16* __restrict__ outb,
    const __bf16* __restrict__ Wl, const __bf16* __restrict__ Wr,
    const float* __restrict__ bias, int n_nodes)
{
    const int t = threadIdx.x, lane = t & 63, w = t >> 6;
    const int base = blockIdx.x * 128;
    const int wr = w >> 1, wc = w & 1;
    const int l31 = lane & 31, kq = lane >> 5;
    const int R0 = base + wr * 64 + l31;   // rows padded to Np (in-bounds reads)
    const int R1 = R0 + 32;
    const int col0 = wc * 64 + l31;

    const __bf16* mA0 = (const __bf16*)mb + (size_t)R0 * HDIM + kq * 8;
    const __bf16* mA1 = (const __bf16*)mb + (size_t)R1 * HDIM + kq * 8;
    const __bf16* hA0 = (const __bf16*)hb + (size_t)R0 * HDIM + kq * 8;
    const __bf16* hA1 = (const __bf16*)hb + (size_t)R1 * HDIM + kq * 8;
    const __bf16* Bl0 = Wl + (size_t)col0 * HDIM + kq * 8;
    const __bf16* Bl1 = Wl + (size_t)(col0 + 32) * HDIM + kq * 8;
    const __bf16* Br0 = Wr + (size_t)col0 * HDIM + kq * 8;
    const __bf16* Br1 = Wr + (size_t)(col0 + 32) * HDIM + kq * 8;

    f32x16 acc[2][2] = {};

#pragma unroll
    for (int k = 0; k < 8; ++k) {   // m half, K=0..127
        bf16x8 af0 = *(const bf16x8*)(mA0 + k * 16);
        bf16x8 af1 = *(const bf16x8*)(mA1 + k * 16);
        bf16x8 b0  = *(const bf16x8*)(Bl0 + k * 16);
        bf16x8 b1  = *(const bf16x8*)(Bl1 + k * 16);
        acc[0][0] = __builtin_amdgcn_mfma_f32_32x32x16_bf16(af0, b0, acc[0][0], 0, 0, 0);
        acc[0][1] = __builtin_amdgcn_mfma_f32_32x32x16_bf16(af0, b1, acc[0][1], 0, 0, 0);
        acc[1][0] = __builtin_amdgcn_mfma_f32_32x32x16_bf16(af1, b0, acc[1][0], 0, 0, 0);
        acc[1][1] = __builtin_amdgcn_mfma_f32_32x32x16_bf16(af1, b1, acc[1][1], 0, 0, 0);
    }
#pragma unroll
    for (int k = 0; k < 8; ++k) {   // h half, K=128..255
        bf16x8 af0 = *(const bf16x8*)(hA0 + k * 16);
        bf16x8 af1 = *(const bf16x8*)(hA1 + k * 16);
        bf16x8 b0  = *(const bf16x8*)(Br0 + k * 16);
        bf16x8 b1  = *(const bf16x8*)(Br1 + k * 16);
        acc[0][0] = __builtin_amdgcn_mfma_f32_32x32x16_bf16(af0, b0, acc[0][0], 0, 0, 0);
        acc[0][1] = __builtin_amdgcn_mfma_f32_32x32x16_bf16(af0, b1, acc[0][1], 0, 0, 0);
        acc[1][0] = __builtin_amdgcn_mfma_f32_32x32x16_bf16(af1, b0, acc[1][0], 0, 0, 0);
        acc[1][1] = __builtin_amdgcn_mfma_f32_32x32x16_bf16(af1, b1, acc[1][1], 0, 0, 0);
    }

    // epilogue: C/D layout (32x32): col = lane&31, row = (reg&3)+8*(reg>>2)+4*(lane>>5)
#pragma unroll
    for (int i = 0; i < 2; ++i) {
#pragma unroll
        for (int j = 0; j < 2; ++j) {
            int C = wc * 64 + j * 32 + l31;
            float bv = bias[C];
#pragma unroll
            for (int r = 0; r < 16; ++r) {
                int row = (r & 3) + 8 * (r >> 2) + 4 * kq;
                int R = base + wr * 64 + i * 32 + row;
                if (R >= n_nodes) continue;
                float v = acc[i][j][r] + bv;
                v = (v > 0.f) ? v : (expf(v) - 1.f);
                if (res) v += __uint_as_float(((uint32)res[(size_t)R * HDIM + C]) << 16);
                __bf16 bb = (__bf16)v;
                outb[(size_t)R * HDIM + C] = __builtin_bit_cast(u16, bb);
            }
        }
    }
}

// ---------------- readout: sigmoid(h3 . Wo + bo), h3 in bf16 ----------------

__global__ __launch_bounds__(256) void readout(
    const uint32* __restrict__ h, const float* __restrict__ Wo,
    const float* __restrict__ bo, float* __restrict__ out, int n_nodes)
{
    int t = threadIdx.x;
    int n = t >> 4, l = t & 15;
    int node = blockIdx.x * 16 + n;
    if (node >= n_nodes) return;
    float s = 0.f;
    for (int j = l; j < 64; j += 16) {
        uint32 v = h[(size_t)node * 64 + j];
        s += bflo(v) * Wo[2 * j] + bfhi(v) * Wo[2 * j + 1];
    }
    for (int o = 8; o; o >>= 1) s += __shfl_down(s, o, 16);
    if (l == 0) out[node] = 1.f / (1.f + expf(-(s + bo[0])));
}

// ---------------- launch ----------------

extern "C" void kernel_launch(void* const* d_in, const int* in_sizes, int n_in,
                              void* d_out, int out_size, void* d_ws, size_t ws_size,
                              hipStream_t stream) {
    const float* x   = (const float*)d_in[0];
    const int*   ei  = (const int*)d_in[1];
    const float* W1l = (const float*)d_in[2];
    const float* b1  = (const float*)d_in[3];
    const float* W1r = (const float*)d_in[4];
    const float* W2l = (const float*)d_in[5];
    const float* b2  = (const float*)d_in[6];
    const float* W2r = (const float*)d_in[7];
    const float* W3l = (const float*)d_in[8];
    const float* b3  = (const float*)d_in[9];
    const float* W3r = (const float*)d_in[10];
    const float* Wo  = (const float*)d_in[11];
    const float* bo  = (const float*)d_in[12];
    float* out = (float*)d_out;

    const int N_ = in_sizes[0] / HDIM;
    const int E_ = in_sizes[1] / 2;
    const int Np = (N_ + 127) & ~127;
    const int nbk = (N_ + BW - 1) / BW;

    size_t o = 0;
    auto carve = [&](size_t bytes) { size_t r = o; o = (o + bytes + 255) & ~255ULL; return r; };
    char* ws = (char*)d_ws;
    int* off        = (int*)(ws + carve((size_t)(N_ + 1) * 4));
    int* bucketCnt  = (int*)(ws + carve((size_t)NBKMAX * 4));
    int* bucketBase = (int*)(ws + carve((size_t)NBKMAX * 4));
    int* srcs       = (int*)(ws + carve((size_t)E_ * 4));
    uint32* tmp     = (uint32*)(ws + carve((size_t)nbk * BCAP * 4));
    __bf16* WB      = (__bf16*)(ws + carve((size_t)6 * HDIM * HDIM * 2));
    uint32* XB      = (uint32*)(ws + carve((size_t)Np * 64 * 4));  // x / h2
    uint32* H1B     = (uint32*)(ws + carve((size_t)Np * 64 * 4));  // h1 / h3
    uint32* MB      = (uint32*)(ws + carve((size_t)Np * 64 * 4));  // aggregated max
    (void)ws_size; (void)n_in; (void)out_size;

    __bf16* W1lb = WB + 0 * HDIM * HDIM;
    __bf16* W1rb = WB + 1 * HDIM * HDIM;
    __bf16* W2lb = WB + 2 * HDIM * HDIM;
    __bf16* W2rb = WB + 3 * HDIM * HDIM;
    __bf16* W3lb = WB + 4 * HDIM * HDIM;
    __bf16* W3rb = WB + 5 * HDIM * HDIM;

    // CSR build (bucketed; also produces off[])
    hipMemsetAsync(bucketCnt, 0, (size_t)NBKMAX * 4, stream);
    bucket_bin<<<(E_ + CHUNK - 1) / CHUNK, 256, 0, stream>>>(ei, E_, nbk, bucketCnt, tmp);
    bucket_scan<<<1, 256, 0, stream>>>(bucketCnt, bucketBase, nbk, off, N_, E_);
    bucket_csr<<<nbk, 256, 0, stream>>>(tmp, bucketCnt, bucketBase, off, srcs, N_);

    // casts
    cast_weights<<<(6 * HDIM * HDIM) / 256, 256, 0, stream>>>(W1l, W1r, W2l, W2r, W3l, W3r, WB);
    cast_x<<<(N_ * 64 + 255) / 256, 256, 0, stream>>>(x, XB, N_ * 64);

    const int nbG = (N_ + 3) / 4;
    const int nbM = Np / 128;

    // layer 1: h1 = elu(W1l m + b1 + W1r x)
    gather_max<<<nbG, 256, 0, stream>>>(XB, MB, off, srcs, N_);
    gemm_layer<<<nbM, 256, 0, stream>>>((const u16*)MB, (const u16*)XB, nullptr,
                                        (u16*)H1B, W1lb, W1rb, b1, N_);
    // layer 2: h2 = elu(...) + h1  -> XB
    gather_max<<<nbG, 256, 0, stream>>>(H1B, MB, off, srcs, N_);
    gemm_layer<<<nbM, 256, 0, stream>>>((const u16*)MB, (const u16*)H1B, (const u16*)H1B,
                                        (u16*)XB, W2lb, W2rb, b2, N_);
    // layer 3: h3 = elu(...) + h2  -> H1B
    gather_max<<<nbG, 256, 0, stream>>>(XB, MB, off, srcs, N_);
    gemm_layer<<<nbM, 256, 0, stream>>>((const u16*)MB, (const u16*)XB, (const u16*)XB,
                                        (u16*)H1B, W3lb, W3rb, b3, N_);

    readout<<<(N_ + 15) / 16, 256, 0, stream>>>(H1B, Wo, bo, out, N_);
}

// Round 8
// 537.942 us; speedup vs baseline: 1.0428x; 1.0428x over previous
//
#include <hip/hip_runtime.h>
#include <math.h>

#define HDIM 128

#define BSHIFT 7
#define BW 128                  // nodes per bucket (dst >> 7)
#define BCAP 4096               // slots per bucket (mean ~2050, ~45 sigma headroom)
#define NBKMAX 1024
#define CHUNK 2048              // edges per bucket_bin block

typedef __attribute__((ext_vector_type(8))) __bf16 bf16x8;
typedef __attribute__((ext_vector_type(16))) float f32x16;
typedef unsigned int uint32;
typedef unsigned short u16;

__device__ __forceinline__ float bflo(uint32 v) { return __uint_as_float(v << 16); }
__device__ __forceinline__ float bfhi(uint32 v) { return __uint_as_float(v & 0xffff0000u); }

// ---------------- CSR build: bucketed two-pass (write-amp ~1) ----------------

__global__ __launch_bounds__(256) void bucket_bin(
    const int* __restrict__ ei, int E_, int nbk,
    int* __restrict__ bucketCnt, uint32* __restrict__ tmp)
{
    __shared__ int cnt[NBKMAX];
    __shared__ int gbase[NBKMAX];
    const int t = threadIdx.x;
    const int start = blockIdx.x * CHUNK;
    const int end = min(start + CHUNK, E_);

    for (int i = t; i < nbk; i += 256) cnt[i] = 0;
    __syncthreads();
    for (int e = start + t; e < end; e += 256)
        atomicAdd(&cnt[ei[E_ + e] >> BSHIFT], 1);
    __syncthreads();
    for (int i = t; i < nbk; i += 256) {
        int c = cnt[i];
        gbase[i] = c ? atomicAdd(&bucketCnt[i], c) : 0;
    }
    __syncthreads();
    for (int i = t; i < nbk; i += 256) cnt[i] = 0;
    __syncthreads();
    for (int e = start + t; e < end; e += 256) {
        int d = ei[E_ + e];
        int s = ei[e];
        int b = d >> BSHIFT;
        int r = atomicAdd(&cnt[b], 1);
        tmp[(size_t)b * BCAP + gbase[b] + r] =
            ((uint32)(d & (BW - 1)) << 17) | (uint32)s;
    }
}

// exclusive scan of bucket counts (nbk <= 1024), set off[N]=E
__global__ __launch_bounds__(1024) void bucket_scan(
    const int* __restrict__ bucketCnt, int* __restrict__ bucketBase,
    int nbk, int* __restrict__ off, int N_, int E_) {
    __shared__ int sd[1024];
    int t = threadIdx.x;
    int v = (t < nbk) ? bucketCnt[t] : 0;
    sd[t] = v;
    __syncthreads();
    for (int ofs = 1; ofs < 1024; ofs <<= 1) {
        int add = (t >= ofs) ? sd[t - ofs] : 0;
        __syncthreads();
        sd[t] += add;
        __syncthreads();
    }
    if (t < nbk) bucketBase[t] = sd[t] - v;
    if (t == 0) off[N_] = E_;
}

__global__ __launch_bounds__(256) void bucket_csr(
    const uint32* __restrict__ tmp, const int* __restrict__ bucketCnt,
    const int* __restrict__ bucketBase,
    int* __restrict__ off, int* __restrict__ srcs, int N_)
{
    __shared__ int lc[BW];   // counts -> cursors
    __shared__ int lo[BW];   // exclusive offsets
    __shared__ int sd[256];
    const int b = blockIdx.x, t = threadIdx.x;
    const int cnt = bucketCnt[b], base = bucketBase[b];
    const uint32* tp = tmp + (size_t)b * BCAP;

    if (t < BW) lc[t] = 0;
    __syncthreads();
    for (int i = t; i < cnt; i += 256) atomicAdd(&lc[tp[i] >> 17], 1);
    __syncthreads();

    int v = (t < BW) ? lc[t] : 0;
    sd[t] = v;
    __syncthreads();
    for (int ofs = 1; ofs < 256; ofs <<= 1) {
        int add = (t >= ofs) ? sd[t - ofs] : 0;
        __syncthreads();
        sd[t] += add;
        __syncthreads();
    }
    if (t < BW) lo[t] = sd[t] - v;
    __syncthreads();

    for (int i = t; i < BW; i += 256) {
        int node = b * BW + i;
        if (node < N_) off[node] = base + lo[i];
    }
    if (t < BW) lc[t] = lo[t];
    __syncthreads();
    for (int i = t; i < cnt; i += 256) {
        uint32 p = tp[i];
        int dl = p >> 17, s = p & 0x1FFFF;
        int pos = base + atomicAdd(&lc[dl], 1);
        srcs[pos] = s;
    }
}

// ---------------- casts ----------------

__global__ void cast_x(const float* __restrict__ x, uint32* __restrict__ xb, int n2) {
    int i = blockIdx.x * 256 + threadIdx.x;
    if (i >= n2) return;
    float2 v = ((const float2*)x)[i];
    __bf16 a = (__bf16)v.x, b = (__bf16)v.y;
    xb[i] = (uint32)__builtin_bit_cast(u16, a) | ((uint32)__builtin_bit_cast(u16, b) << 16);
}

__global__ void cast_weights(const float* __restrict__ a, const float* __restrict__ b,
                             const float* __restrict__ c, const float* __restrict__ d,
                             const float* __restrict__ e, const float* __restrict__ f,
                             __bf16* __restrict__ out) {
    int i = blockIdx.x * 256 + threadIdx.x;  // 6*16384
    int which = i >> 14, j = i & 16383;
    float v;
    switch (which) {
        case 0: v = a[j]; break;
        case 1: v = b[j]; break;
        case 2: v = c[j]; break;
        case 3: v = d[j]; break;
        case 4: v = e[j]; break;
        default: v = f[j]; break;
    }
    out[i] = (__bf16)v;
}

// ---------------- gather-max: 1 wave/node, 16 lanes x 16B per row ----------------

__global__ __launch_bounds__(256) void gather_max(
    const uint32* __restrict__ hb, uint32* __restrict__ mb,
    const int* __restrict__ off, const int* __restrict__ srcs, int n_nodes)
{
    const int w = threadIdx.x >> 6, lane = threadIdx.x & 63;
    const int node = blockIdx.x * 4 + w;
    if (node >= n_nodes) return;
    const int es = lane >> 4, ch = lane & 15;
    const int e0 = off[node], e1 = off[node + 1];
    const uint4* hp = (const uint4*)hb;

    float m0 = -INFINITY, m1 = -INFINITY, m2 = -INFINITY, m3 = -INFINITY;
    float m4 = -INFINITY, m5 = -INFINITY, m6 = -INFINITY, m7 = -INFINITY;

    int e = e0 + es;
    for (; e + 4 < e1; e += 8) {
        int s0 = srcs[e], s1 = srcs[e + 4];
        uint4 v0 = hp[(size_t)s0 * 16 + ch];
        uint4 v1 = hp[(size_t)s1 * 16 + ch];
        m0 = fmaxf(m0, bflo(v0.x)); m1 = fmaxf(m1, bfhi(v0.x));
        m2 = fmaxf(m2, bflo(v0.y)); m3 = fmaxf(m3, bfhi(v0.y));
        m4 = fmaxf(m4, bflo(v0.z)); m5 = fmaxf(m5, bfhi(v0.z));
        m6 = fmaxf(m6, bflo(v0.w)); m7 = fmaxf(m7, bfhi(v0.w));
        m0 = fmaxf(m0, bflo(v1.x)); m1 = fmaxf(m1, bfhi(v1.x));
        m2 = fmaxf(m2, bflo(v1.y)); m3 = fmaxf(m3, bfhi(v1.y));
        m4 = fmaxf(m4, bflo(v1.z)); m5 = fmaxf(m5, bfhi(v1.z));
        m6 = fmaxf(m6, bflo(v1.w)); m7 = fmaxf(m7, bfhi(v1.w));
    }
    if (e < e1) {
        uint4 v0 = hp[(size_t)srcs[e] * 16 + ch];
        m0 = fmaxf(m0, bflo(v0.x)); m1 = fmaxf(m1, bfhi(v0.x));
        m2 = fmaxf(m2, bflo(v0.y)); m3 = fmaxf(m3, bfhi(v0.y));
        m4 = fmaxf(m4, bflo(v0.z)); m5 = fmaxf(m5, bfhi(v0.z));
        m6 = fmaxf(m6, bflo(v0.w)); m7 = fmaxf(m7, bfhi(v0.w));
    }

#define RED(m) m = fmaxf(m, __shfl_xor(m, 16)); m = fmaxf(m, __shfl_xor(m, 32));
    RED(m0) RED(m1) RED(m2) RED(m3) RED(m4) RED(m5) RED(m6) RED(m7)
#undef RED

    if (es == 0) {
        uint4 r = make_uint4(0u, 0u, 0u, 0u);
        if (e1 > e0) {
            r.x = (__float_as_uint(m0) >> 16) | (__float_as_uint(m1) & 0xffff0000u);
            r.y = (__float_as_uint(m2) >> 16) | (__float_as_uint(m3) & 0xffff0000u);
            r.z = (__float_as_uint(m4) >> 16) | (__float_as_uint(m5) & 0xffff0000u);
            r.w = (__float_as_uint(m6) >> 16) | (__float_as_uint(m7) & 0xffff0000u);
        }
        ((uint4*)mb)[(size_t)node * 16 + ch] = r;
    }
}

// ---------------- dense GEMM, LDS-free, 32x32 per wave (max wave count) --------
// block = 32 rows; wave w covers cols [32w, 32w+32). 12512 waves total at N=100k
// to hide the strided global A-load latency (round-7 post-mortem: grid-starved).

__global__ __launch_bounds__(256) void gemm_layer(
    const u16* __restrict__ mb, const u16* __restrict__ hb,
    const u16* __restrict__ res, u16* __restrict__ outb,
    const __bf16* __restrict__ Wl, const __bf16* __restrict__ Wr,
    const float* __restrict__ bias, int n_nodes)
{
    const int t = threadIdx.x, lane = t & 63, w = t >> 6;
    const int base = blockIdx.x * 32;
    const int l31 = lane & 31, kq = lane >> 5;
    const int R0 = base + l31;            // rows padded to Np (in-bounds reads)
    const int col0 = w * 32 + l31;

    const __bf16* mA = (const __bf16*)mb + (size_t)R0 * HDIM + kq * 8;
    const __bf16* hA = (const __bf16*)hb + (size_t)R0 * HDIM + kq * 8;
    const __bf16* Bl = Wl + (size_t)col0 * HDIM + kq * 8;
    const __bf16* Br = Wr + (size_t)col0 * HDIM + kq * 8;

    f32x16 acc = {};

#pragma unroll
    for (int k = 0; k < 8; ++k) {   // m half, K=0..127
        bf16x8 a = *(const bf16x8*)(mA + k * 16);
        bf16x8 b = *(const bf16x8*)(Bl + k * 16);
        acc = __builtin_amdgcn_mfma_f32_32x32x16_bf16(a, b, acc, 0, 0, 0);
    }
#pragma unroll
    for (int k = 0; k < 8; ++k) {   // h half, K=128..255
        bf16x8 a = *(const bf16x8*)(hA + k * 16);
        bf16x8 b = *(const bf16x8*)(Br + k * 16);
        acc = __builtin_amdgcn_mfma_f32_32x32x16_bf16(a, b, acc, 0, 0, 0);
    }

    // epilogue: C/D layout (32x32): col = lane&31, row = (reg&3)+8*(reg>>2)+4*(lane>>5)
    const int C = col0;
    const float bv = bias[C];
#pragma unroll
    for (int r = 0; r < 16; ++r) {
        int row = (r & 3) + 8 * (r >> 2) + 4 * kq;
        int R = base + row;
        if (R >= n_nodes) continue;
        float v = acc[r] + bv;
        v = (v > 0.f) ? v : (expf(v) - 1.f);
        if (res) v += __uint_as_float(((uint32)res[(size_t)R * HDIM + C]) << 16);
        __bf16 bb = (__bf16)v;
        outb[(size_t)R * HDIM + C] = __builtin_bit_cast(u16, bb);
    }
}

// ---------------- readout: sigmoid(h3 . Wo + bo), h3 in bf16 ----------------

__global__ __launch_bounds__(256) void readout(
    const uint32* __restrict__ h, const float* __restrict__ Wo,
    const float* __restrict__ bo, float* __restrict__ out, int n_nodes)
{
    int t = threadIdx.x;
    int n = t >> 4, l = t & 15;
    int node = blockIdx.x * 16 + n;
    if (node >= n_nodes) return;
    float s = 0.f;
    for (int j = l; j < 64; j += 16) {
        uint32 v = h[(size_t)node * 64 + j];
        s += bflo(v) * Wo[2 * j] + bfhi(v) * Wo[2 * j + 1];
    }
    for (int o = 8; o; o >>= 1) s += __shfl_down(s, o, 16);
    if (l == 0) out[node] = 1.f / (1.f + expf(-(s + bo[0])));
}

// ---------------- launch ----------------

extern "C" void kernel_launch(void* const* d_in, const int* in_sizes, int n_in,
                              void* d_out, int out_size, void* d_ws, size_t ws_size,
                              hipStream_t stream) {
    const float* x   = (const float*)d_in[0];
    const int*   ei  = (const int*)d_in[1];
    const float* W1l = (const float*)d_in[2];
    const float* b1  = (const float*)d_in[3];
    const float* W1r = (const float*)d_in[4];
    const float* W2l = (const float*)d_in[5];
    const float* b2  = (const float*)d_in[6];
    const float* W2r = (const float*)d_in[7];
    const float* W3l = (const float*)d_in[8];
    const float* b3  = (const float*)d_in[9];
    const float* W3r = (const float*)d_in[10];
    const float* Wo  = (const float*)d_in[11];
    const float* bo  = (const float*)d_in[12];
    float* out = (float*)d_out;

    const int N_ = in_sizes[0] / HDIM;
    const int E_ = in_sizes[1] / 2;
    const int Np = (N_ + 127) & ~127;
    const int nbk = (N_ + BW - 1) / BW;   // 782 for N=100k (<= NBKMAX)

    size_t o = 0;
    auto carve = [&](size_t bytes) { size_t r = o; o = (o + bytes + 255) & ~255ULL; return r; };
    char* ws = (char*)d_ws;
    int* off        = (int*)(ws + carve((size_t)(N_ + 1) * 4));
    int* bucketCnt  = (int*)(ws + carve((size_t)NBKMAX * 4));
    int* bucketBase = (int*)(ws + carve((size_t)NBKMAX * 4));
    int* srcs       = (int*)(ws + carve((size_t)E_ * 4));
    uint32* tmp     = (uint32*)(ws + carve((size_t)nbk * BCAP * 4));
    __bf16* WB      = (__bf16*)(ws + carve((size_t)6 * HDIM * HDIM * 2));
    uint32* XB      = (uint32*)(ws + carve((size_t)Np * 64 * 4));  // x / h2
    uint32* H1B     = (uint32*)(ws + carve((size_t)Np * 64 * 4));  // h1 / h3
    uint32* MB      = (uint32*)(ws + carve((size_t)Np * 64 * 4));  // aggregated max
    (void)ws_size; (void)n_in; (void)out_size;

    __bf16* W1lb = WB + 0 * HDIM * HDIM;
    __bf16* W1rb = WB + 1 * HDIM * HDIM;
    __bf16* W2lb = WB + 2 * HDIM * HDIM;
    __bf16* W2rb = WB + 3 * HDIM * HDIM;
    __bf16* W3lb = WB + 4 * HDIM * HDIM;
    __bf16* W3rb = WB + 5 * HDIM * HDIM;

    // CSR build (bucketed; also produces off[])
    hipMemsetAsync(bucketCnt, 0, (size_t)NBKMAX * 4, stream);
    bucket_bin<<<(E_ + CHUNK - 1) / CHUNK, 256, 0, stream>>>(ei, E_, nbk, bucketCnt, tmp);
    bucket_scan<<<1, 1024, 0, stream>>>(bucketCnt, bucketBase, nbk, off, N_, E_);
    bucket_csr<<<nbk, 256, 0, stream>>>(tmp, bucketCnt, bucketBase, off, srcs, N_);

    // casts
    cast_weights<<<(6 * HDIM * HDIM) / 256, 256, 0, stream>>>(W1l, W1r, W2l, W2r, W3l, W3r, WB);
    cast_x<<<(N_ * 64 + 255) / 256, 256, 0, stream>>>(x, XB, N_ * 64);

    const int nbG = (N_ + 3) / 4;
    const int nbM = Np / 32;            // 32 rows per block, 4 waves of 32x32

    // layer 1: h1 = elu(W1l m + b1 + W1r x)
    gather_max<<<nbG, 256, 0, stream>>>(XB, MB, off, srcs, N_);
    gemm_layer<<<nbM, 256, 0, stream>>>((const u16*)MB, (const u16*)XB, nullptr,
                                        (u16*)H1B, W1lb, W1rb, b1, N_);
    // layer 2: h2 = elu(...) + h1  -> XB
    gather_max<<<nbG, 256, 0, stream>>>(H1B, MB, off, srcs, N_);
    gemm_layer<<<nbM, 256, 0, stream>>>((const u16*)MB, (const u16*)H1B, (const u16*)H1B,
                                        (u16*)XB, W2lb, W2rb, b2, N_);
    // layer 3: h3 = elu(...) + h2  -> H1B
    gather_max<<<nbG, 256, 0, stream>>>(XB, MB, off, srcs, N_);
    gemm_layer<<<nbM, 256, 0, stream>>>((const u16*)MB, (const u16*)XB, (const u16*)XB,
                                        (u16*)H1B, W3lb, W3rb, b3, N_);

    readout<<<(N_ + 15) / 16, 256, 0, stream>>>(H1B, Wo, bo, out, N_);
}

// Round 10
// 523.851 us; speedup vs baseline: 1.0708x; 1.0269x over previous
//
#include <hip/hip_runtime.h>
#include <hip/hip_fp16.h>
#include <math.h>

#define HDIM 128

#define BSHIFT 7
#define BW 128                  // nodes per bucket (dst >> 7)
#define BCAP 4096               // slots per bucket
#define NBKMAX 1024
#define CHUNK 2048              // edges per bucket_bin block

typedef __attribute__((ext_vector_type(8))) _Float16 f16x8;
typedef __attribute__((ext_vector_type(2))) _Float16 f16x2;
typedef __attribute__((ext_vector_type(16))) float f32x16;
typedef unsigned int uint32;
typedef unsigned short u16;

// packed fp16 max -> v_pk_max_f16
__device__ __forceinline__ uint32 hmax2u(uint32 a, uint32 b) {
    f16x2 ha = __builtin_bit_cast(f16x2, a);
    f16x2 hb = __builtin_bit_cast(f16x2, b);
    f16x2 r = __builtin_elementwise_max(ha, hb);
    return __builtin_bit_cast(uint32, r);
}

// ---------------- CSR build: bucketed two-pass (write-amp ~1) ----------------

__global__ __launch_bounds__(256) void bucket_bin(
    const int* __restrict__ ei, int E_, int nbk,
    int* __restrict__ bucketCnt, uint32* __restrict__ tmp)
{
    __shared__ int cnt[NBKMAX];
    __shared__ int gbase[NBKMAX];
    const int t = threadIdx.x;
    const int start = blockIdx.x * CHUNK;
    const int end = min(start + CHUNK, E_);

    for (int i = t; i < nbk; i += 256) cnt[i] = 0;
    __syncthreads();
    for (int e = start + t; e < end; e += 256)
        atomicAdd(&cnt[ei[E_ + e] >> BSHIFT], 1);
    __syncthreads();
    for (int i = t; i < nbk; i += 256) {
        int c = cnt[i];
        gbase[i] = c ? atomicAdd(&bucketCnt[i], c) : 0;
    }
    __syncthreads();
    for (int i = t; i < nbk; i += 256) cnt[i] = 0;
    __syncthreads();
    for (int e = start + t; e < end; e += 256) {
        int d = ei[E_ + e];
        int s = ei[e];
        int b = d >> BSHIFT;
        int r = atomicAdd(&cnt[b], 1);
        tmp[(size_t)b * BCAP + gbase[b] + r] =
            ((uint32)(d & (BW - 1)) << 17) | (uint32)s;
    }
}

__global__ __launch_bounds__(1024) void bucket_scan(
    const int* __restrict__ bucketCnt, int* __restrict__ bucketBase,
    int nbk, int* __restrict__ off, int N_, int E_) {
    __shared__ int sd[1024];
    int t = threadIdx.x;
    int v = (t < nbk) ? bucketCnt[t] : 0;
    sd[t] = v;
    __syncthreads();
    for (int ofs = 1; ofs < 1024; ofs <<= 1) {
        int add = (t >= ofs) ? sd[t - ofs] : 0;
        __syncthreads();
        sd[t] += add;
        __syncthreads();
    }
    if (t < nbk) bucketBase[t] = sd[t] - v;
    if (t == 0) off[N_] = E_;
}

__global__ __launch_bounds__(256) void bucket_csr(
    const uint32* __restrict__ tmp, const int* __restrict__ bucketCnt,
    const int* __restrict__ bucketBase,
    int* __restrict__ off, int* __restrict__ srcs, int N_)
{
    __shared__ int lc[BW];
    __shared__ int lo[BW];
    __shared__ int sd[256];
    const int b = blockIdx.x, t = threadIdx.x;
    const int cnt = bucketCnt[b], base = bucketBase[b];
    const uint32* tp = tmp + (size_t)b * BCAP;

    if (t < BW) lc[t] = 0;
    __syncthreads();
    for (int i = t; i < cnt; i += 256) atomicAdd(&lc[tp[i] >> 17], 1);
    __syncthreads();

    int v = (t < BW) ? lc[t] : 0;
    sd[t] = v;
    __syncthreads();
    for (int ofs = 1; ofs < 256; ofs <<= 1) {
        int add = (t >= ofs) ? sd[t - ofs] : 0;
        __syncthreads();
        sd[t] += add;
        __syncthreads();
    }
    if (t < BW) lo[t] = sd[t] - v;
    __syncthreads();

    for (int i = t; i < BW; i += 256) {
        int node = b * BW + i;
        if (node < N_) off[node] = base + lo[i];
    }
    if (t < BW) lc[t] = lo[t];
    __syncthreads();
    for (int i = t; i < cnt; i += 256) {
        uint32 p = tp[i];
        int dl = p >> 17, s = p & 0x1FFFF;
        int pos = base + atomicAdd(&lc[dl], 1);
        srcs[pos] = s;
    }
}

// ---------------- casts (fp32 -> fp16) ----------------

__global__ void cast_x(const float* __restrict__ x, uint32* __restrict__ xb, int n2) {
    int i = blockIdx.x * 256 + threadIdx.x;
    if (i >= n2) return;
    float2 v = ((const float2*)x)[i];
    f16x2 h = { (_Float16)v.x, (_Float16)v.y };
    xb[i] = __builtin_bit_cast(uint32, h);
}

__global__ void cast_weights(const float* __restrict__ a, const float* __restrict__ b,
                             const float* __restrict__ c, const float* __restrict__ d,
                             const float* __restrict__ e, const float* __restrict__ f,
                             _Float16* __restrict__ out) {
    int i = blockIdx.x * 256 + threadIdx.x;  // 6*16384
    int which = i >> 14, j = i & 16383;
    float v;
    switch (which) {
        case 0: v = a[j]; break;
        case 1: v = b[j]; break;
        case 2: v = c[j]; break;
        case 3: v = d[j]; break;
        case 4: v = e[j]; break;
        default: v = f[j]; break;
    }
    out[i] = (_Float16)v;
}

// ---------------- gather-max: fp16 packed max, 1 wave/node, 4 rows in flight ----

__global__ __launch_bounds__(256) void gather_max(
    const uint32* __restrict__ hb,   // [Np,64] packed half2
    uint32* __restrict__ mb,         // [Np,64] packed half2
    const int* __restrict__ off, const int* __restrict__ srcs, int n_nodes)
{
    const int w = threadIdx.x >> 6, lane = threadIdx.x & 63;
    const int node = blockIdx.x * 4 + w;
    if (node >= n_nodes) return;
    const int es = lane >> 4, ch = lane & 15;
    const int e0 = off[node], e1 = off[node + 1];
    const uint4* hp = (const uint4*)hb;

    const uint32 NINF = 0xFC00FC00u;   // half2(-inf,-inf)
    uint32 m0 = NINF, m1 = NINF, m2 = NINF, m3 = NINF;

    int e = e0 + es;
    for (; e + 12 < e1; e += 16) {     // 4 rows in flight per lane
        int s0 = srcs[e], s1 = srcs[e + 4], s2 = srcs[e + 8], s3 = srcs[e + 12];
        uint4 v0 = hp[(size_t)s0 * 16 + ch];
        uint4 v1 = hp[(size_t)s1 * 16 + ch];
        uint4 v2 = hp[(size_t)s2 * 16 + ch];
        uint4 v3 = hp[(size_t)s3 * 16 + ch];
        m0 = hmax2u(m0, v0.x); m1 = hmax2u(m1, v0.y);
        m2 = hmax2u(m2, v0.z); m3 = hmax2u(m3, v0.w);
        m0 = hmax2u(m0, v1.x); m1 = hmax2u(m1, v1.y);
        m2 = hmax2u(m2, v1.z); m3 = hmax2u(m3, v1.w);
        m0 = hmax2u(m0, v2.x); m1 = hmax2u(m1, v2.y);
        m2 = hmax2u(m2, v2.z); m3 = hmax2u(m3, v2.w);
        m0 = hmax2u(m0, v3.x); m1 = hmax2u(m1, v3.y);
        m2 = hmax2u(m2, v3.z); m3 = hmax2u(m3, v3.w);
    }
    for (; e < e1; e += 4) {
        uint4 v0 = hp[(size_t)srcs[e] * 16 + ch];
        m0 = hmax2u(m0, v0.x); m1 = hmax2u(m1, v0.y);
        m2 = hmax2u(m2, v0.z); m3 = hmax2u(m3, v0.w);
    }

    // max across the 4 edge-slots (lanes differing in bits 4,5)
    m0 = hmax2u(m0, __shfl_xor(m0, 16)); m0 = hmax2u(m0, __shfl_xor(m0, 32));
    m1 = hmax2u(m1, __shfl_xor(m1, 16)); m1 = hmax2u(m1, __shfl_xor(m1, 32));
    m2 = hmax2u(m2, __shfl_xor(m2, 16)); m2 = hmax2u(m2, __shfl_xor(m2, 32));
    m3 = hmax2u(m3, __shfl_xor(m3, 16)); m3 = hmax2u(m3, __shfl_xor(m3, 32));

    if (es == 0) {
        uint4 r = make_uint4(0u, 0u, 0u, 0u);
        if (e1 > e0) { r.x = m0; r.y = m1; r.z = m2; r.w = m3; }
        ((uint4*)mb)[(size_t)node * 16 + ch] = r;
    }
}

// ---------------- dense GEMM, LDS-free, 32x32 per wave, fp16 MFMA --------------

__global__ __launch_bounds__(256) void gemm_layer(
    const u16* __restrict__ mb, const u16* __restrict__ hb,
    const u16* __restrict__ res, u16* __restrict__ outb,
    const _Float16* __restrict__ Wl, const _Float16* __restrict__ Wr,
    const float* __restrict__ bias, int n_nodes)
{
    const int t = threadIdx.x, lane = t & 63, w = t >> 6;
    const int base = blockIdx.x * 32;
    const int l31 = lane & 31, kq = lane >> 5;
    const int R0 = base + l31;            // rows padded to Np (in-bounds reads)
    const int col0 = w * 32 + l31;

    const _Float16* mA = (const _Float16*)mb + (size_t)R0 * HDIM + kq * 8;
    const _Float16* hA = (const _Float16*)hb + (size_t)R0 * HDIM + kq * 8;
    const _Float16* Bl = Wl + (size_t)col0 * HDIM + kq * 8;
    const _Float16* Br = Wr + (size_t)col0 * HDIM + kq * 8;

    f32x16 acc = {};

#pragma unroll
    for (int k = 0; k < 8; ++k) {   // m half, K=0..127
        f16x8 a = *(const f16x8*)(mA + k * 16);
        f16x8 b = *(const f16x8*)(Bl + k * 16);
        acc = __builtin_amdgcn_mfma_f32_32x32x16_f16(a, b, acc, 0, 0, 0);
    }
#pragma unroll
    for (int k = 0; k < 8; ++k) {   // h half, K=128..255
        f16x8 a = *(const f16x8*)(hA + k * 16);
        f16x8 b = *(const f16x8*)(Br + k * 16);
        acc = __builtin_amdgcn_mfma_f32_32x32x16_f16(a, b, acc, 0, 0, 0);
    }

    // epilogue: C/D layout (32x32): col = lane&31, row = (reg&3)+8*(reg>>2)+4*(lane>>5)
    const int C = col0;
    const float bv = bias[C];
#pragma unroll
    for (int r = 0; r < 16; ++r) {
        int row = (r & 3) + 8 * (r >> 2) + 4 * kq;
        int R = base + row;
        if (R >= n_nodes) continue;
        float v = acc[r] + bv;
        v = (v > 0.f) ? v : (expf(v) - 1.f);
        if (res) v += (float)__builtin_bit_cast(_Float16, res[(size_t)R * HDIM + C]);
        _Float16 hv = (_Float16)v;
        outb[(size_t)R * HDIM + C] = __builtin_bit_cast(u16, hv);
    }
}

// ---------------- readout: sigmoid(h3 . Wo + bo), h3 in fp16 ----------------

__global__ __launch_bounds__(256) void readout(
    const uint32* __restrict__ h, const float* __restrict__ Wo,
    const float* __restrict__ bo, float* __restrict__ out, int n_nodes)
{
    int t = threadIdx.x;
    int n = t >> 4, l = t & 15;
    int node = blockIdx.x * 16 + n;
    if (node >= n_nodes) return;
    float s = 0.f;
    for (int j = l; j < 64; j += 16) {
        uint32 v = h[(size_t)node * 64 + j];
        f16x2 hh = __builtin_bit_cast(f16x2, v);
        s += (float)hh.x * Wo[2 * j] + (float)hh.y * Wo[2 * j + 1];
    }
    for (int o = 8; o; o >>= 1) s += __shfl_down(s, o, 16);
    if (l == 0) out[node] = 1.f / (1.f + expf(-(s + bo[0])));
}

// ---------------- launch ----------------

extern "C" void kernel_launch(void* const* d_in, const int* in_sizes, int n_in,
                              void* d_out, int out_size, void* d_ws, size_t ws_size,
                              hipStream_t stream) {
    const float* x   = (const float*)d_in[0];
    const int*   ei  = (const int*)d_in[1];
    const float* W1l = (const float*)d_in[2];
    const float* b1  = (const float*)d_in[3];
    const float* W1r = (const float*)d_in[4];
    const float* W2l = (const float*)d_in[5];
    const float* b2  = (const float*)d_in[6];
    const float* W2r = (const float*)d_in[7];
    const float* W3l = (const float*)d_in[8];
    const float* b3  = (const float*)d_in[9];
    const float* W3r = (const float*)d_in[10];
    const float* Wo  = (const float*)d_in[11];
    const float* bo  = (const float*)d_in[12];
    float* out = (float*)d_out;

    const int N_ = in_sizes[0] / HDIM;
    const int E_ = in_sizes[1] / 2;
    const int Np = (N_ + 127) & ~127;
    const int nbk = (N_ + BW - 1) / BW;   // 782 for N=100k

    size_t o = 0;
    auto carve = [&](size_t bytes) { size_t r = o; o = (o + bytes + 255) & ~255ULL; return r; };
    char* ws = (char*)d_ws;
    int* off        = (int*)(ws + carve((size_t)(N_ + 1) * 4));
    int* bucketCnt  = (int*)(ws + carve((size_t)NBKMAX * 4));
    int* bucketBase = (int*)(ws + carve((size_t)NBKMAX * 4));
    int* srcs       = (int*)(ws + carve((size_t)E_ * 4));
    uint32* tmp     = (uint32*)(ws + carve((size_t)nbk * BCAP * 4));
    _Float16* WB    = (_Float16*)(ws + carve((size_t)6 * HDIM * HDIM * 2));
    uint32* XB      = (uint32*)(ws + carve((size_t)Np * 64 * 4));  // x / h2
    uint32* H1B     = (uint32*)(ws + carve((size_t)Np * 64 * 4));  // h1 / h3
    uint32* MB      = (uint32*)(ws + carve((size_t)Np * 64 * 4));  // aggregated max
    (void)ws_size; (void)n_in; (void)out_size;

    _Float16* W1lb = WB + 0 * HDIM * HDIM;
    _Float16* W1rb = WB + 1 * HDIM * HDIM;
    _Float16* W2lb = WB + 2 * HDIM * HDIM;
    _Float16* W2rb = WB + 3 * HDIM * HDIM;
    _Float16* W3lb = WB + 4 * HDIM * HDIM;
    _Float16* W3rb = WB + 5 * HDIM * HDIM;

    // CSR build (bucketed; also produces off[])
    (void)hipMemsetAsync(bucketCnt, 0, (size_t)NBKMAX * 4, stream);
    bucket_bin<<<(E_ + CHUNK - 1) / CHUNK, 256, 0, stream>>>(ei, E_, nbk, bucketCnt, tmp);
    bucket_scan<<<1, 1024, 0, stream>>>(bucketCnt, bucketBase, nbk, off, N_, E_);
    bucket_csr<<<nbk, 256, 0, stream>>>(tmp, bucketCnt, bucketBase, off, srcs, N_);

    // casts
    cast_weights<<<(6 * HDIM * HDIM) / 256, 256, 0, stream>>>(W1l, W1r, W2l, W2r, W3l, W3r, WB);
    cast_x<<<(N_ * 64 + 255) / 256, 256, 0, stream>>>(x, XB, N_ * 64);

    const int nbG = (N_ + 3) / 4;
    const int nbM = Np / 32;            // 32 rows per block, 4 waves of 32x32

    // layer 1: h1 = elu(W1l m + b1 + W1r x)
    gather_max<<<nbG, 256, 0, stream>>>(XB, MB, off, srcs, N_);
    gemm_layer<<<nbM, 256, 0, stream>>>((const u16*)MB, (const u16*)XB, nullptr,
                                        (u16*)H1B, W1lb, W1rb, b1, N_);
    // layer 2: h2 = elu(...) + h1  -> XB
    gather_max<<<nbG, 256, 0, stream>>>(H1B, MB, off, srcs, N_);
    gemm_layer<<<nbM, 256, 0, stream>>>((const u16*)MB, (const u16*)H1B, (const u16*)H1B,
                                        (u16*)XB, W2lb, W2rb, b2, N_);
    // layer 3: h3 = elu(...) + h2  -> H1B
    gather_max<<<nbG, 256, 0, stream>>>(XB, MB, off, srcs, N_);
    gemm_layer<<<nbM, 256, 0, stream>>>((const u16*)MB, (const u16*)XB, (const u16*)XB,
                                        (u16*)H1B, W3lb, W3rb, b3, N_);

    readout<<<(N_ + 15) / 16, 256, 0, stream>>>(H1B, Wo, bo, out, N_);
}

// Round 11
// 431.871 us; speedup vs baseline: 1.2989x; 1.2130x over previous
//
#include <hip/hip_runtime.h>
#include <hip/hip_fp16.h>
#include <math.h>

#define HDIM 128

#define BSHIFT 7
#define BW 128                  // nodes per bucket (dst >> 7)
#define BCAP 4096               // slots per bucket
#define NBKMAX 1024
#define CHUNK 2048              // edges per bucket_bin block

typedef __attribute__((ext_vector_type(8))) _Float16 f16x8;
typedef __attribute__((ext_vector_type(2))) _Float16 f16x2;
typedef __attribute__((ext_vector_type(16))) float f32x16;
typedef unsigned int uint32;
typedef unsigned short u16;

// packed fp16 max -> v_pk_max_f16
__device__ __forceinline__ uint32 hmax2u(uint32 a, uint32 b) {
    f16x2 ha = __builtin_bit_cast(f16x2, a);
    f16x2 hb = __builtin_bit_cast(f16x2, b);
    f16x2 r = __builtin_elementwise_max(ha, hb);
    return __builtin_bit_cast(uint32, r);
}

// ---------------- CSR build: bucketed two-pass (write-amp ~1) ----------------

__global__ __launch_bounds__(256) void bucket_bin(
    const int* __restrict__ ei, int E_, int nbk,
    int* __restrict__ bucketCnt, uint32* __restrict__ tmp)
{
    __shared__ int cnt[NBKMAX];
    __shared__ int gbase[NBKMAX];
    const int t = threadIdx.x;
    const int start = blockIdx.x * CHUNK;
    const int end = min(start + CHUNK, E_);

    for (int i = t; i < nbk; i += 256) cnt[i] = 0;
    __syncthreads();
    for (int e = start + t; e < end; e += 256)
        atomicAdd(&cnt[ei[E_ + e] >> BSHIFT], 1);
    __syncthreads();
    for (int i = t; i < nbk; i += 256) {
        int c = cnt[i];
        gbase[i] = c ? atomicAdd(&bucketCnt[i], c) : 0;
    }
    __syncthreads();
    for (int i = t; i < nbk; i += 256) cnt[i] = 0;
    __syncthreads();
    for (int e = start + t; e < end; e += 256) {
        int d = ei[E_ + e];
        int s = ei[e];
        int b = d >> BSHIFT;
        int r = atomicAdd(&cnt[b], 1);
        tmp[(size_t)b * BCAP + gbase[b] + r] =
            ((uint32)(d & (BW - 1)) << 17) | (uint32)s;
    }
}

__global__ __launch_bounds__(1024) void bucket_scan(
    const int* __restrict__ bucketCnt, int* __restrict__ bucketBase,
    int nbk, int* __restrict__ off, int N_, int E_) {
    __shared__ int sd[1024];
    int t = threadIdx.x;
    int v = (t < nbk) ? bucketCnt[t] : 0;
    sd[t] = v;
    __syncthreads();
    for (int ofs = 1; ofs < 1024; ofs <<= 1) {
        int add = (t >= ofs) ? sd[t - ofs] : 0;
        __syncthreads();
        sd[t] += add;
        __syncthreads();
    }
    if (t < nbk) bucketBase[t] = sd[t] - v;
    if (t == 0) off[N_] = E_;
}

__global__ __launch_bounds__(256) void bucket_csr(
    const uint32* __restrict__ tmp, const int* __restrict__ bucketCnt,
    const int* __restrict__ bucketBase,
    int* __restrict__ off, int* __restrict__ srcs, int N_)
{
    __shared__ int lc[BW];
    __shared__ int lo[BW];
    __shared__ int sd[256];
    const int b = blockIdx.x, t = threadIdx.x;
    const int cnt = bucketCnt[b], base = bucketBase[b];
    const uint32* tp = tmp + (size_t)b * BCAP;

    if (t < BW) lc[t] = 0;
    __syncthreads();
    for (int i = t; i < cnt; i += 256) atomicAdd(&lc[tp[i] >> 17], 1);
    __syncthreads();

    int v = (t < BW) ? lc[t] : 0;
    sd[t] = v;
    __syncthreads();
    for (int ofs = 1; ofs < 256; ofs <<= 1) {
        int add = (t >= ofs) ? sd[t - ofs] : 0;
        __syncthreads();
        sd[t] += add;
        __syncthreads();
    }
    if (t < BW) lo[t] = sd[t] - v;
    __syncthreads();

    for (int i = t; i < BW; i += 256) {
        int node = b * BW + i;
        if (node < N_) off[node] = base + lo[i];
    }
    if (t < BW) lc[t] = lo[t];
    __syncthreads();
    for (int i = t; i < cnt; i += 256) {
        uint32 p = tp[i];
        int dl = p >> 17, s = p & 0x1FFFF;
        int pos = base + atomicAdd(&lc[dl], 1);
        srcs[pos] = s;
    }
}

// ---------------- casts ----------------

__global__ void cast_x(const float* __restrict__ x, uint32* __restrict__ xb, int n2) {
    int i = blockIdx.x * 256 + threadIdx.x;
    if (i >= n2) return;
    float2 v = ((const float2*)x)[i];
    f16x2 h = { (_Float16)v.x, (_Float16)v.y };
    xb[i] = __builtin_bit_cast(uint32, h);
}

// pack weights into frag-major layout: PW[layer][(g*16+ks)*64+lane] = 16B frag,
// frag elements = W[col=g*32+(lane&31)][(ks&7)*16 + (lane>>5)*8 + j], ks<8 -> Wl else Wr
__global__ void cast_weights_packed(
    const float* __restrict__ W1l, const float* __restrict__ W1r,
    const float* __restrict__ W2l, const float* __restrict__ W2r,
    const float* __restrict__ W3l, const float* __restrict__ W3r,
    f16x8* __restrict__ PW)
{
    int tid = blockIdx.x * 256 + threadIdx.x;   // 3*4096 frags
    if (tid >= 3 * 4096) return;
    int layer = tid >> 12, rem = tid & 4095;
    int g = rem >> 10, ks = (rem >> 6) & 15, lane = rem & 63;
    int col = g * 32 + (lane & 31), kq = lane >> 5;
    const float* src;
    if (layer == 0)      src = (ks < 8) ? W1l : W1r;
    else if (layer == 1) src = (ks < 8) ? W2l : W2r;
    else                 src = (ks < 8) ? W3l : W3r;
    int kk = (ks & 7) * 16 + kq * 8;
    f16x8 v;
#pragma unroll
    for (int j = 0; j < 8; ++j) v[j] = (_Float16)src[col * HDIM + kk + j];
    PW[tid] = v;
}

// ---------------- gather-max: fp16 packed max, 1 wave/node, 4 rows in flight ----

__global__ __launch_bounds__(256) void gather_max(
    const uint32* __restrict__ hb,   // [Np,64] packed half2
    uint32* __restrict__ mb,         // [Np,64] packed half2
    const int* __restrict__ off, const int* __restrict__ srcs, int n_nodes)
{
    const int w = threadIdx.x >> 6, lane = threadIdx.x & 63;
    const int node = blockIdx.x * 4 + w;
    if (node >= n_nodes) return;
    const int es = lane >> 4, ch = lane & 15;
    const int e0 = off[node], e1 = off[node + 1];
    const uint4* hp = (const uint4*)hb;

    const uint32 NINF = 0xFC00FC00u;   // half2(-inf,-inf)
    uint32 m0 = NINF, m1 = NINF, m2 = NINF, m3 = NINF;

    int e = e0 + es;
    for (; e + 12 < e1; e += 16) {     // 4 rows in flight per lane
        int s0 = srcs[e], s1 = srcs[e + 4], s2 = srcs[e + 8], s3 = srcs[e + 12];
        uint4 v0 = hp[(size_t)s0 * 16 + ch];
        uint4 v1 = hp[(size_t)s1 * 16 + ch];
        uint4 v2 = hp[(size_t)s2 * 16 + ch];
        uint4 v3 = hp[(size_t)s3 * 16 + ch];
        m0 = hmax2u(m0, v0.x); m1 = hmax2u(m1, v0.y);
        m2 = hmax2u(m2, v0.z); m3 = hmax2u(m3, v0.w);
        m0 = hmax2u(m0, v1.x); m1 = hmax2u(m1, v1.y);
        m2 = hmax2u(m2, v1.z); m3 = hmax2u(m3, v1.w);
        m0 = hmax2u(m0, v2.x); m1 = hmax2u(m1, v2.y);
        m2 = hmax2u(m2, v2.z); m3 = hmax2u(m3, v2.w);
        m0 = hmax2u(m0, v3.x); m1 = hmax2u(m1, v3.y);
        m2 = hmax2u(m2, v3.z); m3 = hmax2u(m3, v3.w);
    }
    for (; e < e1; e += 4) {
        uint4 v0 = hp[(size_t)srcs[e] * 16 + ch];
        m0 = hmax2u(m0, v0.x); m1 = hmax2u(m1, v0.y);
        m2 = hmax2u(m2, v0.z); m3 = hmax2u(m3, v0.w);
    }

    m0 = hmax2u(m0, __shfl_xor(m0, 16)); m0 = hmax2u(m0, __shfl_xor(m0, 32));
    m1 = hmax2u(m1, __shfl_xor(m1, 16)); m1 = hmax2u(m1, __shfl_xor(m1, 32));
    m2 = hmax2u(m2, __shfl_xor(m2, 16)); m2 = hmax2u(m2, __shfl_xor(m2, 32));
    m3 = hmax2u(m3, __shfl_xor(m3, 16)); m3 = hmax2u(m3, __shfl_xor(m3, 32));

    if (es == 0) {
        uint4 r = make_uint4(0u, 0u, 0u, 0u);
        if (e1 > e0) { r.x = m0; r.y = m1; r.z = m2; r.w = m3; }
        ((uint4*)mb)[(size_t)node * 16 + ch] = r;
    }
}

// ---------------- dense GEMM: swizzled-LDS A-tile + packed B-frags ----------------
// Block = 32 rows × 128 cols, 4 waves (one 32x32 tile each). A staged into LDS with
// XOR swizzle chunk^(row&7) -> balanced 8/bank (wave64-b128 minimum). B-frags read
// from frag-major PW: base + lane*16 = dense 16 lines/instr (vs 32 sparse before).

__global__ __launch_bounds__(256) void gemm_layer(
    const uint4* __restrict__ mb, const uint4* __restrict__ hb,
    const u16* __restrict__ res, u16* __restrict__ outb,
    const uint4* __restrict__ PW,       // [4096] packed frags for this layer
    const float* __restrict__ bias, int n_nodes)
{
    __shared__ uint4 sm[512];   // m-tile: 32 rows x 16 chunks (8 KiB)
    __shared__ uint4 sh[512];   // h-tile
    const int t = threadIdx.x, lane = t & 63, w = t >> 6;
    const int base = blockIdx.x * 32;
    const int l31 = lane & 31, kq = lane >> 5;

    // stage A tiles, coalesced (16 threads x 16B per row), swizzled store
#pragma unroll
    for (int r = 0; r < 2; ++r) {
        int g = r * 256 + t;            // 0..511
        int row = g >> 4, ch = g & 15;
        int sw = ch ^ (row & 7);
        size_t gi = (size_t)(base + row) * 16 + ch;
        sm[row * 16 + sw] = mb[gi];
        sh[row * 16 + sw] = hb[gi];
    }
    __syncthreads();

    f32x16 acc = {};

#pragma unroll
    for (int k = 0; k < 8; ++k) {   // m half, K=0..127
        f16x8 a = __builtin_bit_cast(f16x8, sm[l31 * 16 + ((2 * k + kq) ^ (l31 & 7))]);
        f16x8 b = __builtin_bit_cast(f16x8, PW[(w * 16 + k) * 64 + lane]);
        acc = __builtin_amdgcn_mfma_f32_32x32x16_f16(a, b, acc, 0, 0, 0);
    }
#pragma unroll
    for (int k = 0; k < 8; ++k) {   // h half, K=128..255
        f16x8 a = __builtin_bit_cast(f16x8, sh[l31 * 16 + ((2 * k + kq) ^ (l31 & 7))]);
        f16x8 b = __builtin_bit_cast(f16x8, PW[(w * 16 + 8 + k) * 64 + lane]);
        acc = __builtin_amdgcn_mfma_f32_32x32x16_f16(a, b, acc, 0, 0, 0);
    }

    // epilogue: C/D layout (32x32): col = lane&31, row = (reg&3)+8*(reg>>2)+4*(lane>>5)
    const int C = w * 32 + l31;
    const float bv = bias[C];
#pragma unroll
    for (int r = 0; r < 16; ++r) {
        int row = (r & 3) + 8 * (r >> 2) + 4 * kq;
        int R = base + row;
        if (R >= n_nodes) continue;
        float v = acc[r] + bv;
        v = (v > 0.f) ? v : (expf(v) - 1.f);
        if (res) v += (float)__builtin_bit_cast(_Float16, res[(size_t)R * HDIM + C]);
        _Float16 hv = (_Float16)v;
        outb[(size_t)R * HDIM + C] = __builtin_bit_cast(u16, hv);
    }
}

// ---------------- readout: sigmoid(h3 . Wo + bo), h3 in fp16 ----------------

__global__ __launch_bounds__(256) void readout(
    const uint32* __restrict__ h, const float* __restrict__ Wo,
    const float* __restrict__ bo, float* __restrict__ out, int n_nodes)
{
    int t = threadIdx.x;
    int n = t >> 4, l = t & 15;
    int node = blockIdx.x * 16 + n;
    if (node >= n_nodes) return;
    float s = 0.f;
    for (int j = l; j < 64; j += 16) {
        uint32 v = h[(size_t)node * 64 + j];
        f16x2 hh = __builtin_bit_cast(f16x2, v);
        s += (float)hh.x * Wo[2 * j] + (float)hh.y * Wo[2 * j + 1];
    }
    for (int o = 8; o; o >>= 1) s += __shfl_down(s, o, 16);
    if (l == 0) out[node] = 1.f / (1.f + expf(-(s + bo[0])));
}

// ---------------- launch ----------------

extern "C" void kernel_launch(void* const* d_in, const int* in_sizes, int n_in,
                              void* d_out, int out_size, void* d_ws, size_t ws_size,
                              hipStream_t stream) {
    const float* x   = (const float*)d_in[0];
    const int*   ei  = (const int*)d_in[1];
    const float* W1l = (const float*)d_in[2];
    const float* b1  = (const float*)d_in[3];
    const float* W1r = (const float*)d_in[4];
    const float* W2l = (const float*)d_in[5];
    const float* b2  = (const float*)d_in[6];
    const float* W2r = (const float*)d_in[7];
    const float* W3l = (const float*)d_in[8];
    const float* b3  = (const float*)d_in[9];
    const float* W3r = (const float*)d_in[10];
    const float* Wo  = (const float*)d_in[11];
    const float* bo  = (const float*)d_in[12];
    float* out = (float*)d_out;

    const int N_ = in_sizes[0] / HDIM;
    const int E_ = in_sizes[1] / 2;
    const int Np = (N_ + 127) & ~127;
    const int nbk = (N_ + BW - 1) / BW;   // 782 for N=100k

    size_t o = 0;
    auto carve = [&](size_t bytes) { size_t r = o; o = (o + bytes + 255) & ~255ULL; return r; };
    char* ws = (char*)d_ws;
    int* off        = (int*)(ws + carve((size_t)(N_ + 1) * 4));
    int* bucketCnt  = (int*)(ws + carve((size_t)NBKMAX * 4));
    int* bucketBase = (int*)(ws + carve((size_t)NBKMAX * 4));
    int* srcs       = (int*)(ws + carve((size_t)E_ * 4));
    uint32* tmp     = (uint32*)(ws + carve((size_t)nbk * BCAP * 4));
    uint4* PW       = (uint4*)(ws + carve((size_t)3 * 4096 * 16));
    uint32* XB      = (uint32*)(ws + carve((size_t)Np * 64 * 4));  // x / h2
    uint32* H1B     = (uint32*)(ws + carve((size_t)Np * 64 * 4));  // h1 / h3
    uint32* MB      = (uint32*)(ws + carve((size_t)Np * 64 * 4));  // aggregated max
    (void)ws_size; (void)n_in; (void)out_size;

    // CSR build (bucketed; also produces off[])
    (void)hipMemsetAsync(bucketCnt, 0, (size_t)NBKMAX * 4, stream);
    bucket_bin<<<(E_ + CHUNK - 1) / CHUNK, 256, 0, stream>>>(ei, E_, nbk, bucketCnt, tmp);
    bucket_scan<<<1, 1024, 0, stream>>>(bucketCnt, bucketBase, nbk, off, N_, E_);
    bucket_csr<<<nbk, 256, 0, stream>>>(tmp, bucketCnt, bucketBase, off, srcs, N_);

    // casts
    cast_weights_packed<<<(3 * 4096 + 255) / 256, 256, 0, stream>>>(
        W1l, W1r, W2l, W2r, W3l, W3r, (f16x8*)PW);
    cast_x<<<(N_ * 64 + 255) / 256, 256, 0, stream>>>(x, XB, N_ * 64);

    const int nbG = (N_ + 3) / 4;
    const int nbM = Np / 32;            // 32 rows per block, 4 waves of 32x32

    const uint4* PW1 = PW;
    const uint4* PW2 = PW + 4096;
    const uint4* PW3 = PW + 8192;

    // layer 1: h1 = elu(W1l m + b1 + W1r x)
    gather_max<<<nbG, 256, 0, stream>>>(XB, MB, off, srcs, N_);
    gemm_layer<<<nbM, 256, 0, stream>>>((const uint4*)MB, (const uint4*)XB, nullptr,
                                        (u16*)H1B, PW1, b1, N_);
    // layer 2: h2 = elu(...) + h1  -> XB
    gather_max<<<nbG, 256, 0, stream>>>(H1B, MB, off, srcs, N_);
    gemm_layer<<<nbM, 256, 0, stream>>>((const uint4*)MB, (const uint4*)H1B, (const u16*)H1B,
                                        (u16*)XB, PW2, b2, N_);
    // layer 3: h3 = elu(...) + h2  -> H1B
    gather_max<<<nbG, 256, 0, stream>>>(XB, MB, off, srcs, N_);
    gemm_layer<<<nbM, 256, 0, stream>>>((const uint4*)MB, (const uint4*)XB, (const u16*)XB,
                                        (u16*)H1B, PW3, b3, N_);

    readout<<<(N_ + 15) / 16, 256, 0, stream>>>(H1B, Wo, bo, out, N_);
}

// Round 12
// 401.970 us; speedup vs baseline: 1.3955x; 1.0744x over previous
//
#include <hip/hip_runtime.h>
#include <hip/hip_fp16.h>
#include <math.h>

#define HDIM 128

#define BSHIFT 7
#define BW 128                  // nodes per bucket (dst >> 7)
#define BCAP 4096               // slots per bucket
#define NBKMAX 1024
#define CHUNK 4096              // edges per bucket_bin block

typedef __attribute__((ext_vector_type(8))) _Float16 f16x8;
typedef __attribute__((ext_vector_type(2))) _Float16 f16x2;
typedef __attribute__((ext_vector_type(16))) float f32x16;
typedef unsigned int uint32;
typedef unsigned short u16;

// packed fp16 max -> v_pk_max_f16
__device__ __forceinline__ uint32 hmax2u(uint32 a, uint32 b) {
    f16x2 ha = __builtin_bit_cast(f16x2, a);
    f16x2 hb = __builtin_bit_cast(f16x2, b);
    f16x2 r = __builtin_elementwise_max(ha, hb);
    return __builtin_bit_cast(uint32, r);
}
// packed fp16 add -> v_pk_add_f16
__device__ __forceinline__ uint32 hadd2u(uint32 a, uint32 b) {
    f16x2 ha = __builtin_bit_cast(f16x2, a);
    f16x2 hb = __builtin_bit_cast(f16x2, b);
    f16x2 r = ha + hb;
    return __builtin_bit_cast(uint32, r);
}

// ---------------- CSR build: bucketed two-pass (write-amp ~1) ----------------

__global__ __launch_bounds__(256) void bucket_bin(
    const int* __restrict__ ei, int E_, int nbk,
    int* __restrict__ bucketCnt, uint32* __restrict__ tmp)
{
    __shared__ int cnt[NBKMAX];
    __shared__ int gbase[NBKMAX];
    const int t = threadIdx.x;
    const int start = blockIdx.x * CHUNK;
    const int end = min(start + CHUNK, E_);

    for (int i = t; i < nbk; i += 256) cnt[i] = 0;
    __syncthreads();
    for (int e = start + t; e < end; e += 256)
        atomicAdd(&cnt[ei[E_ + e] >> BSHIFT], 1);
    __syncthreads();
    for (int i = t; i < nbk; i += 256) {
        int c = cnt[i];
        gbase[i] = c ? atomicAdd(&bucketCnt[i], c) : 0;
    }
    __syncthreads();
    for (int i = t; i < nbk; i += 256) cnt[i] = 0;
    __syncthreads();
    for (int e = start + t; e < end; e += 256) {
        int d = ei[E_ + e];
        int s = ei[e];
        int b = d >> BSHIFT;
        int r = atomicAdd(&cnt[b], 1);
        tmp[(size_t)b * BCAP + gbase[b] + r] =
            ((uint32)(d & (BW - 1)) << 17) | (uint32)s;
    }
}

__global__ __launch_bounds__(1024) void bucket_scan(
    const int* __restrict__ bucketCnt, int* __restrict__ bucketBase,
    int nbk, int* __restrict__ off, int N_, int E_) {
    __shared__ int sd[1024];
    int t = threadIdx.x;
    int v = (t < nbk) ? bucketCnt[t] : 0;
    sd[t] = v;
    __syncthreads();
    for (int ofs = 1; ofs < 1024; ofs <<= 1) {
        int add = (t >= ofs) ? sd[t - ofs] : 0;
        __syncthreads();
        sd[t] += add;
        __syncthreads();
    }
    if (t < nbk) bucketBase[t] = sd[t] - v;
    if (t == 0) off[N_] = E_;
}

__global__ __launch_bounds__(256) void bucket_csr(
    const uint32* __restrict__ tmp, const int* __restrict__ bucketCnt,
    const int* __restrict__ bucketBase,
    int* __restrict__ off, int* __restrict__ srcs, int N_)
{
    __shared__ int lc[BW];
    __shared__ int lo[BW];
    __shared__ int sd[256];
    const int b = blockIdx.x, t = threadIdx.x;
    const int cnt = bucketCnt[b], base = bucketBase[b];
    const uint32* tp = tmp + (size_t)b * BCAP;

    if (t < BW) lc[t] = 0;
    __syncthreads();
    for (int i = t; i < cnt; i += 256) atomicAdd(&lc[tp[i] >> 17], 1);
    __syncthreads();

    int v = (t < BW) ? lc[t] : 0;
    sd[t] = v;
    __syncthreads();
    for (int ofs = 1; ofs < 256; ofs <<= 1) {
        int add = (t >= ofs) ? sd[t - ofs] : 0;
        __syncthreads();
        sd[t] += add;
        __syncthreads();
    }
    if (t < BW) lo[t] = sd[t] - v;
    __syncthreads();

    for (int i = t; i < BW; i += 256) {
        int node = b * BW + i;
        if (node < N_) off[node] = base + lo[i];
    }
    if (t < BW) lc[t] = lo[t];
    __syncthreads();
    for (int i = t; i < cnt; i += 256) {
        uint32 p = tp[i];
        int dl = p >> 17, s = p & 0x1FFFF;
        int pos = base + atomicAdd(&lc[dl], 1);
        srcs[pos] = s;
    }
}

// ---------------- casts ----------------

__global__ void cast_x(const float* __restrict__ x, uint32* __restrict__ xb, int n2) {
    int i = blockIdx.x * 256 + threadIdx.x;
    if (i >= n2) return;
    float2 v = ((const float2*)x)[i];
    f16x2 h = { (_Float16)v.x, (_Float16)v.y };
    xb[i] = __builtin_bit_cast(uint32, h);
}

// pack weights into frag-major layout: PW[layer][(g*16+ks)*64+lane] = 16B frag,
// frag elements = W[col=g*32+(lane&31)][(ks&7)*16 + (lane>>5)*8 + j], ks<8 -> Wl else Wr
__global__ void cast_weights_packed(
    const float* __restrict__ W1l, const float* __restrict__ W1r,
    const float* __restrict__ W2l, const float* __restrict__ W2r,
    const float* __restrict__ W3l, const float* __restrict__ W3r,
    f16x8* __restrict__ PW)
{
    int tid = blockIdx.x * 256 + threadIdx.x;   // 3*4096 frags
    if (tid >= 3 * 4096) return;
    int layer = tid >> 12, rem = tid & 4095;
    int g = rem >> 10, ks = (rem >> 6) & 15, lane = rem & 63;
    int col = g * 32 + (lane & 31), kq = lane >> 5;
    const float* src;
    if (layer == 0)      src = (ks < 8) ? W1l : W1r;
    else if (layer == 1) src = (ks < 8) ? W2l : W2r;
    else                 src = (ks < 8) ? W3l : W3r;
    int kk = (ks & 7) * 16 + kq * 8;
    f16x8 v;
#pragma unroll
    for (int j = 0; j < 8; ++j) v[j] = (_Float16)src[col * HDIM + kk + j];
    PW[tid] = v;
}

// ---------------- gather-max: fp16 packed max, 1 wave/node, 4 rows in flight ----

__global__ __launch_bounds__(256) void gather_max(
    const uint32* __restrict__ hb,   // [Np,64] packed half2
    uint32* __restrict__ mb,         // [Np,64] packed half2
    const int* __restrict__ off, const int* __restrict__ srcs, int n_nodes)
{
    const int w = threadIdx.x >> 6, lane = threadIdx.x & 63;
    const int node = blockIdx.x * 4 + w;
    if (node >= n_nodes) return;
    const int es = lane >> 4, ch = lane & 15;
    const int e0 = off[node], e1 = off[node + 1];
    const uint4* hp = (const uint4*)hb;

    const uint32 NINF = 0xFC00FC00u;   // half2(-inf,-inf)
    uint32 m0 = NINF, m1 = NINF, m2 = NINF, m3 = NINF;

    int e = e0 + es;
    for (; e + 12 < e1; e += 16) {     // 4 rows in flight per lane
        int s0 = srcs[e], s1 = srcs[e + 4], s2 = srcs[e + 8], s3 = srcs[e + 12];
        uint4 v0 = hp[(size_t)s0 * 16 + ch];
        uint4 v1 = hp[(size_t)s1 * 16 + ch];
        uint4 v2 = hp[(size_t)s2 * 16 + ch];
        uint4 v3 = hp[(size_t)s3 * 16 + ch];
        m0 = hmax2u(m0, v0.x); m1 = hmax2u(m1, v0.y);
        m2 = hmax2u(m2, v0.z); m3 = hmax2u(m3, v0.w);
        m0 = hmax2u(m0, v1.x); m1 = hmax2u(m1, v1.y);
        m2 = hmax2u(m2, v1.z); m3 = hmax2u(m3, v1.w);
        m0 = hmax2u(m0, v2.x); m1 = hmax2u(m1, v2.y);
        m2 = hmax2u(m2, v2.z); m3 = hmax2u(m3, v2.w);
        m0 = hmax2u(m0, v3.x); m1 = hmax2u(m1, v3.y);
        m2 = hmax2u(m2, v3.z); m3 = hmax2u(m3, v3.w);
    }
    for (; e < e1; e += 4) {
        uint4 v0 = hp[(size_t)srcs[e] * 16 + ch];
        m0 = hmax2u(m0, v0.x); m1 = hmax2u(m1, v0.y);
        m2 = hmax2u(m2, v0.z); m3 = hmax2u(m3, v0.w);
    }

    m0 = hmax2u(m0, __shfl_xor(m0, 16)); m0 = hmax2u(m0, __shfl_xor(m0, 32));
    m1 = hmax2u(m1, __shfl_xor(m1, 16)); m1 = hmax2u(m1, __shfl_xor(m1, 32));
    m2 = hmax2u(m2, __shfl_xor(m2, 16)); m2 = hmax2u(m2, __shfl_xor(m2, 32));
    m3 = hmax2u(m3, __shfl_xor(m3, 16)); m3 = hmax2u(m3, __shfl_xor(m3, 32));

    if (es == 0) {
        uint4 r = make_uint4(0u, 0u, 0u, 0u);
        if (e1 > e0) { r.x = m0; r.y = m1; r.z = m2; r.w = m3; }
        ((uint4*)mb)[(size_t)node * 16 + ch] = r;
    }
}

// ---------------- dense GEMM: swizzled-LDS A-tile + packed B-frags ----------------
// Epilogue routes through an LDS transpose so res/out are accessed as uint4
// (4 global instrs/thread instead of 32 scattered u16 accesses).

#define ESTRIDE 136   // halves per row in epilogue LDS (272 B: banks disjoint, 16B-aligned)

__global__ __launch_bounds__(256) void gemm_layer(
    const uint4* __restrict__ mb, const uint4* __restrict__ hb,
    const uint4* __restrict__ res, uint4* __restrict__ outb,
    const uint4* __restrict__ PW,       // [4096] packed frags for this layer
    const float* __restrict__ bias, int n_nodes)
{
    __shared__ uint4 sm[512];             // m-tile: 32 rows x 16 chunks (8 KiB)
    __shared__ uint4 sh[512];             // h-tile
    __shared__ _Float16 ho[32 * ESTRIDE]; // epilogue transpose (8.5 KiB)
    const int t = threadIdx.x, lane = t & 63, w = t >> 6;
    const int base = blockIdx.x * 32;
    const int l31 = lane & 31, kq = lane >> 5;

    // stage A tiles, coalesced (16 threads x 16B per row), swizzled store
#pragma unroll
    for (int r = 0; r < 2; ++r) {
        int g = r * 256 + t;            // 0..511
        int row = g >> 4, ch = g & 15;
        int sw = ch ^ (row & 7);
        size_t gi = (size_t)(base + row) * 16 + ch;
        sm[row * 16 + sw] = mb[gi];
        sh[row * 16 + sw] = hb[gi];
    }
    __syncthreads();

    f32x16 acc = {};

#pragma unroll
    for (int k = 0; k < 8; ++k) {   // m half, K=0..127
        f16x8 a = __builtin_bit_cast(f16x8, sm[l31 * 16 + ((2 * k + kq) ^ (l31 & 7))]);
        f16x8 b = __builtin_bit_cast(f16x8, PW[(w * 16 + k) * 64 + lane]);
        acc = __builtin_amdgcn_mfma_f32_32x32x16_f16(a, b, acc, 0, 0, 0);
    }
#pragma unroll
    for (int k = 0; k < 8; ++k) {   // h half, K=128..255
        f16x8 a = __builtin_bit_cast(f16x8, sh[l31 * 16 + ((2 * k + kq) ^ (l31 & 7))]);
        f16x8 b = __builtin_bit_cast(f16x8, PW[(w * 16 + 8 + k) * 64 + lane]);
        acc = __builtin_amdgcn_mfma_f32_32x32x16_f16(a, b, acc, 0, 0, 0);
    }

    // epilogue phase 1: bias + ELU in fp32, write fp16 into LDS transpose tile
    // C/D layout (32x32): col = lane&31, row = (reg&3)+8*(reg>>2)+4*(lane>>5)
    const int C = w * 32 + l31;
    const float bv = bias[C];
#pragma unroll
    for (int r = 0; r < 16; ++r) {
        int row = (r & 3) + 8 * (r >> 2) + 4 * kq;
        float v = acc[r] + bv;
        v = (v > 0.f) ? v : (__expf(v) - 1.f);
        ho[row * ESTRIDE + C] = (_Float16)v;
    }
    __syncthreads();

    // epilogue phase 2: row-major uint4 out (+ packed fp16 residual)
#pragma unroll
    for (int r = 0; r < 2; ++r) {
        int g = r * 256 + t;            // 0..511
        int row = g >> 4, ch = g & 15;
        int R = base + row;
        if (R >= n_nodes) continue;
        uint4 v = *(const uint4*)&ho[row * ESTRIDE + ch * 8];
        if (res) {
            uint4 rv = res[(size_t)R * 16 + ch];
            v.x = hadd2u(v.x, rv.x); v.y = hadd2u(v.y, rv.y);
            v.z = hadd2u(v.z, rv.z); v.w = hadd2u(v.w, rv.w);
        }
        outb[(size_t)R * 16 + ch] = v;
    }
}

// ---------------- readout: sigmoid(h3 . Wo + bo), h3 in fp16 ----------------

__global__ __launch_bounds__(256) void readout(
    const uint32* __restrict__ h, const float* __restrict__ Wo,
    const float* __restrict__ bo, float* __restrict__ out, int n_nodes)
{
    int t = threadIdx.x;
    int n = t >> 4, l = t & 15;
    int node = blockIdx.x * 16 + n;
    if (node >= n_nodes) return;
    float s = 0.f;
    for (int j = l; j < 64; j += 16) {
        uint32 v = h[(size_t)node * 64 + j];
        f16x2 hh = __builtin_bit_cast(f16x2, v);
        s += (float)hh.x * Wo[2 * j] + (float)hh.y * Wo[2 * j + 1];
    }
    for (int o = 8; o; o >>= 1) s += __shfl_down(s, o, 16);
    if (l == 0) out[node] = 1.f / (1.f + expf(-(s + bo[0])));
}

// ---------------- launch ----------------

extern "C" void kernel_launch(void* const* d_in, const int* in_sizes, int n_in,
                              void* d_out, int out_size, void* d_ws, size_t ws_size,
                              hipStream_t stream) {
    const float* x   = (const float*)d_in[0];
    const int*   ei  = (const int*)d_in[1];
    const float* W1l = (const float*)d_in[2];
    const float* b1  = (const float*)d_in[3];
    const float* W1r = (const float*)d_in[4];
    const float* W2l = (const float*)d_in[5];
    const float* b2  = (const float*)d_in[6];
    const float* W2r = (const float*)d_in[7];
    const float* W3l = (const float*)d_in[8];
    const float* b3  = (const float*)d_in[9];
    const float* W3r = (const float*)d_in[10];
    const float* Wo  = (const float*)d_in[11];
    const float* bo  = (const float*)d_in[12];
    float* out = (float*)d_out;

    const int N_ = in_sizes[0] / HDIM;
    const int E_ = in_sizes[1] / 2;
    const int Np = (N_ + 127) & ~127;
    const int nbk = (N_ + BW - 1) / BW;   // 782 for N=100k

    size_t o = 0;
    auto carve = [&](size_t bytes) { size_t r = o; o = (o + bytes + 255) & ~255ULL; return r; };
    char* ws = (char*)d_ws;
    int* off        = (int*)(ws + carve((size_t)(N_ + 1) * 4));
    int* bucketCnt  = (int*)(ws + carve((size_t)NBKMAX * 4));
    int* bucketBase = (int*)(ws + carve((size_t)NBKMAX * 4));
    int* srcs       = (int*)(ws + carve((size_t)E_ * 4));
    uint32* tmp     = (uint32*)(ws + carve((size_t)nbk * BCAP * 4));
    uint4* PW       = (uint4*)(ws + carve((size_t)3 * 4096 * 16));
    uint32* XB      = (uint32*)(ws + carve((size_t)Np * 64 * 4));  // x / h2
    uint32* H1B     = (uint32*)(ws + carve((size_t)Np * 64 * 4));  // h1 / h3
    uint32* MB      = (uint32*)(ws + carve((size_t)Np * 64 * 4));  // aggregated max
    (void)ws_size; (void)n_in; (void)out_size;

    // CSR build (bucketed; also produces off[])
    (void)hipMemsetAsync(bucketCnt, 0, (size_t)NBKMAX * 4, stream);
    bucket_bin<<<(E_ + CHUNK - 1) / CHUNK, 256, 0, stream>>>(ei, E_, nbk, bucketCnt, tmp);
    bucket_scan<<<1, 1024, 0, stream>>>(bucketCnt, bucketBase, nbk, off, N_, E_);
    bucket_csr<<<nbk, 256, 0, stream>>>(tmp, bucketCnt, bucketBase, off, srcs, N_);

    // casts
    cast_weights_packed<<<(3 * 4096 + 255) / 256, 256, 0, stream>>>(
        W1l, W1r, W2l, W2r, W3l, W3r, (f16x8*)PW);
    cast_x<<<(N_ * 64 + 255) / 256, 256, 0, stream>>>(x, XB, N_ * 64);

    const int nbG = (N_ + 3) / 4;
    const int nbM = Np / 32;            // 32 rows per block, 4 waves of 32x32

    const uint4* PW1 = PW;
    const uint4* PW2 = PW + 4096;
    const uint4* PW3 = PW + 8192;

    // layer 1: h1 = elu(W1l m + b1 + W1r x)
    gather_max<<<nbG, 256, 0, stream>>>(XB, MB, off, srcs, N_);
    gemm_layer<<<nbM, 256, 0, stream>>>((const uint4*)MB, (const uint4*)XB, nullptr,
                                        (uint4*)H1B, PW1, b1, N_);
    // layer 2: h2 = elu(...) + h1  -> XB
    gather_max<<<nbG, 256, 0, stream>>>(H1B, MB, off, srcs, N_);
    gemm_layer<<<nbM, 256, 0, stream>>>((const uint4*)MB, (const uint4*)H1B, (const uint4*)H1B,
                                        (uint4*)XB, PW2, b2, N_);
    // layer 3: h3 = elu(...) + h2  -> H1B
    gather_max<<<nbG, 256, 0, stream>>>(XB, MB, off, srcs, N_);
    gemm_layer<<<nbM, 256, 0, stream>>>((const uint4*)MB, (const uint4*)XB, (const uint4*)XB,
                                        (uint4*)H1B, PW3, b3, N_);

    readout<<<(N_ + 15) / 16, 256, 0, stream>>>(H1B, Wo, bo, out, N_);
}